// Round 2
// baseline (2550.276 us; speedup 1.0000x reference)
//
#include <hip/hip_runtime.h>
#include <math.h>

// GPT-2 forward, 12 layers, L=1024, D=768, H=12, d=64.
// v3: fused flash attention (no scores/P intermediates), 128^2 m97-structure
// logits GEMM with XCD-chunked swizzle. Layer GEMMs keep the verified 64^2
// BT structure (bf16 operands, global_load_lds staging, XOR swizzle, 0 bank
// conflicts). Residual x stays fp32.

#define SEQ 1024
#define DMODEL 768
#define NHEADS 12
#define HEADD 64
#define ATT_SCALE 0.125f  // 1/sqrt(64)

typedef unsigned short u16;
typedef __bf16 bf16x8 __attribute__((ext_vector_type(8)));
typedef float f32x4 __attribute__((ext_vector_type(4)));

__device__ __forceinline__ u16 bf(float f) {
    return __builtin_bit_cast(u16, (__bf16)f);  // RNE
}

__device__ __forceinline__ void gll16(const u16* g, u16* l) {
    // async global(16B/lane) -> LDS; dest is wave-uniform base + lane*16
    __builtin_amdgcn_global_load_lds(
        (const __attribute__((address_space(1))) unsigned int*)g,
        (__attribute__((address_space(3))) unsigned int*)l, 16, 0, 0);
}

// ---------------------------------------------------------------------------
// BT GEMM 64x64 tile: C[M][N] (=, bf16=, +=) A[M][K] @ B[N][K]^T (+bias,GELU)
// A,B bf16 row-major. BK=64, 256 thr = 4 waves. Verified: 0 bank conflicts.
// Fragments (gfx950, HW-verified m89/m91):
//   A: m=lane&15, k=quad*8+j ; B: n=lane&15, k=quad*8+j ; D: col=lane&15, row=quad*4+r
// MODE: 0 = fp32 store, 1 = bf16 store, 2 = fp32 accumulate.
// ---------------------------------------------------------------------------
template <int MODE, bool GELU, bool BOUND>
__global__ __launch_bounds__(256) void gemm_bt(
    const u16* __restrict__ A, int lda, long aBatch,
    const u16* __restrict__ B, int ldb, long bBatch,
    void* __restrict__ Cv, int ldc, long cBatch,
    const float* __restrict__ bias, int N, int K) {
    __shared__ alignas(16) u16 As[64 * 64];
    __shared__ alignas(16) u16 Bs[64 * 64];

    const int z = blockIdx.z;
    A += (long)z * aBatch;
    B += (long)z * bBatch;

    const int m0 = blockIdx.x * 64;   // m fastest-varying
    const int n0 = blockIdx.y * 64;
    const int t = threadIdx.x;

    const int srow = t >> 3;                          // 0..31 (issue adds 32)
    const int scol = ((t & 7) ^ (srow & 7)) << 3;     // swizzled k-offset (elems)

    const u16* aSrc0 = A + (long)(m0 + srow) * lda + scol;
    const u16* aSrc1 = A + (long)(m0 + srow + 32) * lda + scol;
    int br0 = n0 + srow, br1 = n0 + srow + 32;
    if (BOUND) {
        if (br0 > N - 1) br0 = N - 1;
        if (br1 > N - 1) br1 = N - 1;
    }
    const u16* bSrc0 = B + (long)br0 * ldb + scol;
    const u16* bSrc1 = B + (long)br1 * ldb + scol;

    u16* aDst = &As[t * 8];
    u16* bDst = &Bs[t * 8];

    const int lane = t & 63, w = t >> 6;
    const int quad = lane >> 4, ml = lane & 15;
    const int sw = ml & 7;
    const int arow64 = (w * 16 + ml) * 64;

    f32x4 acc[4] = {f32x4{0, 0, 0, 0}, f32x4{0, 0, 0, 0},
                    f32x4{0, 0, 0, 0}, f32x4{0, 0, 0, 0}};

    for (int k0 = 0; k0 < K; k0 += 64) {
        if (k0) __syncthreads();
        gll16(aSrc0, aDst);
        gll16(aSrc1, aDst + 2048);
        gll16(bSrc0, bDst);
        gll16(bSrc1, bDst + 2048);
        aSrc0 += 64; aSrc1 += 64; bSrc0 += 64; bSrc1 += 64;
        __syncthreads();

        bf16x8 a0 = *(const bf16x8*)&As[arow64 + ((quad ^ sw) << 3)];
        bf16x8 a1 = *(const bf16x8*)&As[arow64 + (((4 + quad) ^ sw) << 3)];
#pragma unroll
        for (int i = 0; i < 4; ++i) {
            const int brow64 = (i * 16 + ml) * 64;
            bf16x8 b0 = *(const bf16x8*)&Bs[brow64 + ((quad ^ sw) << 3)];
            bf16x8 b1 = *(const bf16x8*)&Bs[brow64 + (((4 + quad) ^ sw) << 3)];
            acc[i] = __builtin_amdgcn_mfma_f32_16x16x32_bf16(a0, b0, acc[i], 0, 0, 0);
            acc[i] = __builtin_amdgcn_mfma_f32_16x16x32_bf16(a1, b1, acc[i], 0, 0, 0);
        }
    }

    float* Cf = (float*)Cv + (MODE != 1 ? (long)z * cBatch : 0);
    u16*   Ch = (u16*)Cv  + (MODE == 1 ? (long)z * cBatch : 0);
    const int mrow = m0 + w * 16 + quad * 4;
#pragma unroll
    for (int i = 0; i < 4; ++i) {
        const int col = n0 + i * 16 + ml;
        if (BOUND && col >= N) continue;
        const float bv = bias ? bias[col] : 0.f;
#pragma unroll
        for (int r = 0; r < 4; ++r) {
            float v = acc[i][r] + bv;
            if (GELU) {
                v = 0.5f * v * (1.f + tanhf(0.7978845608028654f * (v + 0.044715f * v * v * v)));
            }
            const long idx = (long)(mrow + r) * ldc + col;
            if (MODE == 0)      Cf[idx] = v;
            else if (MODE == 1) Ch[idx] = bf(v);
            else                Cf[idx] += v;
        }
    }
}

// ---------------------------------------------------------------------------
// 128x128-tile BT GEMM (m97 structure) for the logits matmul.
// BK=64, 256 thr = 4 waves (2x2), each wave 4x4 16x16 frags (64x64).
// XCD-chunked bijective swizzle (requires nwg % 8 == 0): each B-panel's 8
// m-blocks stay on one XCD -> panel fetched once per XCD.
// ---------------------------------------------------------------------------
__global__ __launch_bounds__(256) void gemm_bt128(
    const u16* __restrict__ A, int lda,
    const u16* __restrict__ B, int ldb,
    float* __restrict__ C, int ldc,
    const float* __restrict__ bias, int N, int K) {
    __shared__ alignas(16) u16 As[128 * 64];
    __shared__ alignas(16) u16 Bs[128 * 64];

    const int nwg = gridDim.x * gridDim.y;        // 8 * 393, %8 == 0
    const int lid = blockIdx.x + gridDim.x * blockIdx.y;
    const int per = nwg >> 3;
    const int nl  = (lid & 7) * per + (lid >> 3); // bijective
    const int m0 = (nl & 7) << 7;                 // gridDim.x == 8 m-tiles
    const int n0 = (nl >> 3) << 7;

    const int t = threadIdx.x;
    const int srow = t >> 3;                       // 0..31
    const int scol = ((t & 7) ^ (srow & 7)) << 3;  // (32j preserves row&7)

    const u16* aS = A + (long)(m0 + srow) * lda + scol;
    int brow[4];
#pragma unroll
    for (int j = 0; j < 4; ++j) {
        int rr = n0 + srow + 32 * j;
        brow[j] = rr < N ? rr : N - 1;   // clamp: garbage cols discarded below
    }

    const int lane = t & 63, w = t >> 6;
    const int quad = lane >> 4, ml = lane & 15;
    const int wm = w >> 1, wn = w & 1, sw = ml & 7;

    f32x4 acc[4][4];
#pragma unroll
    for (int a = 0; a < 4; ++a)
#pragma unroll
        for (int b = 0; b < 4; ++b) acc[a][b] = f32x4{0, 0, 0, 0};

    for (int k0 = 0; k0 < K; k0 += 64) {
        if (k0) __syncthreads();
#pragma unroll
        for (int j = 0; j < 4; ++j) {
            gll16(aS + (long)(32 * j) * lda + k0, &As[t * 8 + j * 2048]);
            gll16(B + (long)brow[j] * ldb + k0 + scol, &Bs[t * 8 + j * 2048]);
        }
        __syncthreads();
#pragma unroll
        for (int kh = 0; kh < 2; ++kh) {
            const int so = ((kh * 4 + quad) ^ sw) << 3;
            bf16x8 af[4], bfr[4];
#pragma unroll
            for (int mi = 0; mi < 4; ++mi)
                af[mi] = *(const bf16x8*)&As[(wm * 64 + mi * 16 + ml) * 64 + so];
#pragma unroll
            for (int ni = 0; ni < 4; ++ni)
                bfr[ni] = *(const bf16x8*)&Bs[(wn * 64 + ni * 16 + ml) * 64 + so];
#pragma unroll
            for (int mi = 0; mi < 4; ++mi)
#pragma unroll
                for (int ni = 0; ni < 4; ++ni)
                    acc[mi][ni] = __builtin_amdgcn_mfma_f32_16x16x32_bf16(
                        af[mi], bfr[ni], acc[mi][ni], 0, 0, 0);
        }
    }

#pragma unroll
    for (int mi = 0; mi < 4; ++mi) {
        const int mrow = m0 + wm * 64 + mi * 16 + quad * 4;
#pragma unroll
        for (int ni = 0; ni < 4; ++ni) {
            const int col = n0 + wn * 64 + ni * 16 + ml;
            if (col >= N) continue;
            const float bv = bias ? bias[col] : 0.f;
#pragma unroll
            for (int r = 0; r < 4; ++r)
                C[(long)(mrow + r) * ldc + col] = acc[mi][ni][r] + bv;
        }
    }
}

// ---------------------------------------------------------------------------
// Fused flash attention. Grid (16 q-tiles, 12 heads), 256 thr = 4 waves.
// Wave w owns q-rows q0+w*16..+15. Q/K frags loaded direct from qkvb (L1/L2
// resident tiles), V via precomputed vT. Online softmax per q-row; P goes
// D-frag -> A-frag through a per-wave-private LDS tile (no barriers at all).
// ---------------------------------------------------------------------------
__global__ __launch_bounds__(256) void fattn_kernel(
    const u16* __restrict__ qkvb, const u16* __restrict__ vT,
    u16* __restrict__ attno) {
    __shared__ alignas(16) u16 Pl[4 * 16 * 72];   // per-wave 16x72 (pad 8)
    const int qt = blockIdx.x, h = blockIdx.y;
    const int q0 = qt << 6;
    const int t = threadIdx.x, lane = t & 63, w = t >> 6;
    const int quad = lane >> 4, ml = lane & 15;

    const long qr0 = (long)(q0 + w * 16 + ml) * (3 * DMODEL) + h * 64;
    const bf16x8 qa0 = *(const bf16x8*)&qkvb[qr0 + quad * 8];
    const bf16x8 qa1 = *(const bf16x8*)&qkvb[qr0 + 32 + quad * 8];

    f32x4 o[4] = {f32x4{0, 0, 0, 0}, f32x4{0, 0, 0, 0},
                  f32x4{0, 0, 0, 0}, f32x4{0, 0, 0, 0}};
    float mrow[4] = {-1e30f, -1e30f, -1e30f, -1e30f};
    float lrow[4] = {0.f, 0.f, 0.f, 0.f};

    u16* Pw = &Pl[w * 16 * 72];
    const int nt = qt + 1;

    for (int kt = 0; kt < nt; ++kt) {
        const int kv0 = kt << 6;
        // S-tile = Q @ K^T (wave: 16 q-rows x 64 kv-cols)
        f32x4 s[4];
#pragma unroll
        for (int i = 0; i < 4; ++i) {
            const long kr = (long)(kv0 + i * 16 + ml) * (3 * DMODEL) + DMODEL + h * 64;
            bf16x8 kb0 = *(const bf16x8*)&qkvb[kr + quad * 8];
            bf16x8 kb1 = *(const bf16x8*)&qkvb[kr + 32 + quad * 8];
            f32x4 z = {0, 0, 0, 0};
            z = __builtin_amdgcn_mfma_f32_16x16x32_bf16(qa0, kb0, z, 0, 0, 0);
            z = __builtin_amdgcn_mfma_f32_16x16x32_bf16(qa1, kb1, z, 0, 0, 0);
            s[i] = z;
        }
        const bool diag = (kt == nt - 1);
        // online softmax, rows quad*4+r distributed over the 16 ml lanes
#pragma unroll
        for (int r = 0; r < 4; ++r) {
            float sv[4];
#pragma unroll
            for (int i = 0; i < 4; ++i) sv[i] = s[i][r] * ATT_SCALE;
            if (diag) {
                const int qr = q0 + w * 16 + quad * 4 + r;
#pragma unroll
                for (int i = 0; i < 4; ++i)
                    if (kv0 + i * 16 + ml > qr) sv[i] = -1e30f;
            }
            float mx = fmaxf(fmaxf(sv[0], sv[1]), fmaxf(sv[2], sv[3]));
#pragma unroll
            for (int msk = 1; msk < 16; msk <<= 1)
                mx = fmaxf(mx, __shfl_xor(mx, msk, 64));
            const float mnew = fmaxf(mrow[r], mx);
            const float corr = expf(mrow[r] - mnew);   // 0 on first tile
            mrow[r] = mnew;
            const float p0 = expf(sv[0] - mnew), p1 = expf(sv[1] - mnew);
            const float p2 = expf(sv[2] - mnew), p3 = expf(sv[3] - mnew);
            float rs = (p0 + p1) + (p2 + p3);
#pragma unroll
            for (int msk = 1; msk < 16; msk <<= 1)
                rs += __shfl_xor(rs, msk, 64);
            lrow[r] = lrow[r] * corr + rs;
#pragma unroll
            for (int i = 0; i < 4; ++i) o[i][r] *= corr;
            u16* pr = Pw + (quad * 4 + r) * 72 + ml;
            pr[0] = bf(p0); pr[16] = bf(p1); pr[32] = bf(p2); pr[48] = bf(p3);
        }
        // O += P @ V  (A-frag from Pw transpose, B-frag from vT)
        const bf16x8 pa0 = *(const bf16x8*)&Pw[ml * 72 + quad * 8];
        const bf16x8 pa1 = *(const bf16x8*)&Pw[ml * 72 + 32 + quad * 8];
#pragma unroll
        for (int i = 0; i < 4; ++i) {
            const long vr = (long)(h * 64 + i * 16 + ml) * SEQ + kv0;
            bf16x8 vb0 = *(const bf16x8*)&vT[vr + quad * 8];
            bf16x8 vb1 = *(const bf16x8*)&vT[vr + 32 + quad * 8];
            o[i] = __builtin_amdgcn_mfma_f32_16x16x32_bf16(pa0, vb0, o[i], 0, 0, 0);
            o[i] = __builtin_amdgcn_mfma_f32_16x16x32_bf16(pa1, vb1, o[i], 0, 0, 0);
        }
    }

#pragma unroll
    for (int r = 0; r < 4; ++r) {
        const float inv = 1.f / lrow[r];   // >= 1, never 0
        u16* orow = attno + (long)(q0 + w * 16 + quad * 4 + r) * DMODEL + h * 64;
#pragma unroll
        for (int i = 0; i < 4; ++i) orow[i * 16 + ml] = bf(o[i][r] * inv);
    }
}

// ---------------------------------------------------------------------------
// Per-layer weight transpose+convert: fp32 [K][N] -> bf16 [N][K].
// ---------------------------------------------------------------------------
__global__ __launch_bounds__(256) void wtrans4_kernel(
    const float* __restrict__ aw, const float* __restrict__ apw,
    const float* __restrict__ fw, const float* __restrict__ pw,
    u16* __restrict__ awT, u16* __restrict__ apwT,
    u16* __restrict__ fwT, u16* __restrict__ pwT) {
    int b = blockIdx.x;
    const float* src; u16* dst; int K, N;
    if (b < 432)       { src = aw;  dst = awT;  K = 768;  N = 2304; }
    else if (b < 576)  { src = apw; dst = apwT; K = 768;  N = 768;  b -= 432; }
    else if (b < 1152) { src = fw;  dst = fwT;  K = 768;  N = 3072; b -= 576; }
    else               { src = pw;  dst = pwT;  K = 3072; N = 768;  b -= 1152; }
    const int ntn = N >> 6;
    const int n0 = (b % ntn) << 6, k0 = (b / ntn) << 6;

    __shared__ u16 tile[64][68];
    const int t = threadIdx.x, r = t >> 2, c0 = (t & 3) << 4;

    const float* srow = src + (long)(k0 + r) * N + n0 + c0;
    u16* trow = &tile[r][c0];
#pragma unroll
    for (int j = 0; j < 16; ++j) trow[j] = bf(srow[j]);
    __syncthreads();

    alignas(16) u16 tmp[16];
#pragma unroll
    for (int j = 0; j < 16; ++j) tmp[j] = tile[c0 + j][r];
    u16* drow = dst + (long)(n0 + r) * K + k0 + c0;
    *(uint4*)drow       = *(const uint4*)tmp;
    *(uint4*)(drow + 8) = *(const uint4*)(tmp + 8);
}

// V slice of qkv -> vT[h][d][t] (bf16)
__global__ __launch_bounds__(256) void vtrans_kernel(
    const u16* __restrict__ qkvb, u16* __restrict__ vT) {
    const int t0 = blockIdx.x << 6, h = blockIdx.y;
    __shared__ u16 tile[64][68];
    const int t = threadIdx.x, r = t >> 2, c0 = (t & 3) << 4;
    const u16* srow = qkvb + (long)(t0 + r) * (3 * DMODEL) + 2 * DMODEL + h * HEADD + c0;
#pragma unroll
    for (int j = 0; j < 16; ++j) tile[r][c0 + j] = srow[j];
    __syncthreads();
    alignas(16) u16 tmp[16];
#pragma unroll
    for (int j = 0; j < 16; ++j) tmp[j] = tile[c0 + j][r];
    u16* drow = vT + ((long)h * HEADD + r) * SEQ + t0 + c0;
    *(uint4*)drow       = *(const uint4*)tmp;
    *(uint4*)(drow + 8) = *(const uint4*)(tmp + 8);
}

// fp32 -> bf16 bulk convert (wte for logits)
__global__ __launch_bounds__(256) void cvt_bf16_kernel(
    const float* __restrict__ src, u16* __restrict__ dst, long n8) {
    const float4* sp = (const float4*)src;
    for (long i = blockIdx.x * 256 + threadIdx.x; i < n8; i += (long)gridDim.x * 256) {
        const float4 a = sp[2 * i], b = sp[2 * i + 1];
        alignas(16) u16 o[8] = {bf(a.x), bf(a.y), bf(a.z), bf(a.w),
                                bf(b.x), bf(b.y), bf(b.z), bf(b.w)};
        ((uint4*)dst)[i] = *(const uint4*)o;
    }
}

// ---------------------------------------------------------------------------
__device__ inline float wave_sum(float v) {
#pragma unroll
    for (int o = 32; o > 0; o >>= 1) v += __shfl_xor(v, o, 64);
    return v;
}
__device__ inline float block_sum(float v, float* red) {
    v = wave_sum(v);
    if ((threadIdx.x & 63) == 0) red[threadIdx.x >> 6] = v;
    __syncthreads();
    v = red[0] + red[1] + red[2] + red[3];
    __syncthreads();
    return v;
}

__global__ __launch_bounds__(256) void embed_kernel(
    const int* __restrict__ ids, const float* __restrict__ wte,
    const float* __restrict__ wpe, float* __restrict__ x) {
    const int l = blockIdx.x;
    const long wo = (long)ids[l] * DMODEL;
    const long po = (long)l * DMODEL;
#pragma unroll
    for (int j = 0; j < 3; ++j) {
        const int d = threadIdx.x + j * 256;
        x[po + d] = wte[wo + d] + wpe[po + d];
    }
}

// LayerNorm, fp32 in -> bf16 out
__global__ __launch_bounds__(256) void ln_kernel(
    const float* __restrict__ x, const float* __restrict__ g,
    const float* __restrict__ b, u16* __restrict__ out) {
    __shared__ float red[4];
    const int row = blockIdx.x;
    const float* xr = x + (long)row * DMODEL;
    const int t = threadIdx.x;
    float v0 = xr[t], v1 = xr[t + 256], v2 = xr[t + 512];
    const float mean = block_sum(v0 + v1 + v2, red) * (1.f / DMODEL);
    const float d0 = v0 - mean, d1 = v1 - mean, d2 = v2 - mean;
    const float var = block_sum(d0 * d0 + d1 * d1 + d2 * d2, red) * (1.f / DMODEL);
    const float inv = rsqrtf(var + 1e-5f);
    u16* orow = out + (long)row * DMODEL;
    orow[t]       = bf(d0 * inv * g[t]       + b[t]);
    orow[t + 256] = bf(d1 * inv * g[t + 256] + b[t + 256]);
    orow[t + 512] = bf(d2 * inv * g[t + 512] + b[t + 512]);
}

// ---------------------------------------------------------------------------
extern "C" void kernel_launch(void* const* d_in, const int* in_sizes, int n_in,
                              void* d_out, int out_size, void* d_ws, size_t ws_size,
                              hipStream_t stream) {
    const int* input_ids = (const int*)d_in[0];
    const float* wte     = (const float*)d_in[5];
    const float* wpe     = (const float*)d_in[6];
    const float* ln1_g   = (const float*)d_in[7];
    const float* ln1_b   = (const float*)d_in[8];
    const float* attn_w  = (const float*)d_in[9];
    const float* attn_b  = (const float*)d_in[10];
    const float* attn_pw = (const float*)d_in[11];
    const float* attn_pb = (const float*)d_in[12];
    const float* ln2_g   = (const float*)d_in[13];
    const float* ln2_b   = (const float*)d_in[14];
    const float* fc_w    = (const float*)d_in[15];
    const float* fc_b    = (const float*)d_in[16];
    const float* proj_w  = (const float*)d_in[17];
    const float* proj_b  = (const float*)d_in[18];
    const float* lnf_g   = (const float*)d_in[19];
    const float* lnf_b   = (const float*)d_in[20];

    // workspace carve (~102 MB). wteBF aliases attno/fcact (dead at logits).
    char* p = (char*)d_ws;
    auto carve = [&](long bytes) { char* q = p; p += (bytes + 255) & ~255L; return q; };
    float* x   = (float*)carve((long)SEQ * DMODEL * 4);
    u16* hbf   = (u16*)carve((long)SEQ * DMODEL * 2);
    u16* qkvb  = (u16*)carve((long)SEQ * 3 * DMODEL * 2);
    u16* vT    = (u16*)carve((long)NHEADS * HEADD * SEQ * 2);
    u16* awT   = (u16*)carve((long)2304 * 768 * 2);
    u16* apwT  = (u16*)carve((long)768 * 768 * 2);
    u16* fwT   = (u16*)carve((long)3072 * 768 * 2);
    u16* pwT   = (u16*)carve((long)768 * 3072 * 2);
    char* region = p;
    u16* attno = (u16*)carve((long)SEQ * DMODEL * 2);
    u16* fcact = (u16*)carve((long)SEQ * 4 * DMODEL * 2);
    u16* wteBF = (u16*)region;  // 77.2 MB from region start (nothing carved after)

    embed_kernel<<<SEQ, 256, 0, stream>>>(input_ids, wte, wpe, x);

    for (int i = 0; i < 12; ++i) {
        const float* aw  = attn_w  + (long)i * DMODEL * 3 * DMODEL;
        const float* ab  = attn_b  + (long)i * 3 * DMODEL;
        const float* apw = attn_pw + (long)i * DMODEL * DMODEL;
        const float* apb = attn_pb + (long)i * DMODEL;
        const float* fw  = fc_w    + (long)i * DMODEL * 4 * DMODEL;
        const float* fb  = fc_b    + (long)i * 4 * DMODEL;
        const float* pw  = proj_w  + (long)i * 4 * DMODEL * DMODEL;
        const float* pb  = proj_b  + (long)i * DMODEL;

        wtrans4_kernel<<<1728, 256, 0, stream>>>(aw, apw, fw, pw, awT, apwT, fwT, pwT);

        ln_kernel<<<SEQ, 256, 0, stream>>>(x, ln1_g + i * DMODEL, ln1_b + i * DMODEL, hbf);
        gemm_bt<1, false, false><<<dim3(16, 36, 1), 256, 0, stream>>>(
            hbf, DMODEL, 0, awT, DMODEL, 0, qkvb, 3 * DMODEL, 0, ab, 3 * DMODEL, DMODEL);
        vtrans_kernel<<<dim3(16, NHEADS), 256, 0, stream>>>(qkvb, vT);
        // fused attention: qkvb -> attno (bf16), no intermediates
        fattn_kernel<<<dim3(16, NHEADS), 256, 0, stream>>>(qkvb, vT, attno);
        gemm_bt<2, false, false><<<dim3(16, 12, 1), 256, 0, stream>>>(
            attno, DMODEL, 0, apwT, DMODEL, 0, x, DMODEL, 0, apb, DMODEL, DMODEL);
        ln_kernel<<<SEQ, 256, 0, stream>>>(x, ln2_g + i * DMODEL, ln2_b + i * DMODEL, hbf);
        gemm_bt<1, true, false><<<dim3(16, 48, 1), 256, 0, stream>>>(
            hbf, DMODEL, 0, fwT, DMODEL, 0, fcact, 4 * DMODEL, 0, fb, 4 * DMODEL, DMODEL);
        gemm_bt<2, false, false><<<dim3(16, 12, 1), 256, 0, stream>>>(
            fcact, 4 * DMODEL, 0, pwT, 4 * DMODEL, 0, x, DMODEL, 0, pb, DMODEL, 4 * DMODEL);
    }

    ln_kernel<<<SEQ, 256, 0, stream>>>(x, lnf_g, lnf_b, hbf);
    cvt_bf16_kernel<<<2048, 256, 0, stream>>>(wte, wteBF, (long)50257 * 768 / 8);
    gemm_bt128<<<dim3(8, 393), 256, 0, stream>>>(
        hbf, DMODEL, wteBF, DMODEL, (float*)d_out, 50257, nullptr, 50257, DMODEL);
}